// Round 7
// baseline (96.669 us; speedup 1.0000x reference)
//
#include <hip/hip_runtime.h>

// out[b,n] = relu( sum_d x[b, idx[n,d]] * w[n,d] )
//   x: (B=256, N=16384) f32, w: (N,32) f32, idx: (N,32) i32, out: (B,N) f32
//
// R7 (= R6 with the pkrtz type fixed): L2 random-line gather measured
// ~10-12 TB/s effective (R3/R4/R5 A/Bs falsified byte-BW, segment, and MLP
// theories). Structural fix: gather from LDS. Block = 2 batch rows packed h2
// (exactly 64 KiB LDS) x 8192 n. Random-j ds_read_b32: bank = j%32, uniform.
//   K0: pack idx+w -> pw[d2][n] = { j_lo | j_hi<<16 , h2(w_lo, w_hi) } (2 MiB)
//   K1: stage 2 x-rows -> LDS h2; per n: 16 coalesced dwordx2 pw loads,
//       32 LDS gathers, 64 fma; coalesced dword stores to both out rows.

#define NB   16384
#define DEG  32

typedef __fp16 hp2 __attribute__((ext_vector_type(2)));  // cvt_pkrtz result type

__global__ __launch_bounds__(256) void prep_pw_kernel(
    const int* __restrict__ idx, const float* __restrict__ w,
    uint2* __restrict__ pw) {
    __shared__ int   idx_s[64][33];
    __shared__ float w_s[64][33];
    const int t  = threadIdx.x;
    const int nb = blockIdx.x * 64;

    const int4*   src  = (const int4*)(idx + (size_t)nb * DEG);
    const float4* srcw = (const float4*)(w   + (size_t)nb * DEG);
#pragma unroll
    for (int p = 0; p < 2; ++p) {
        const int e4 = t + 256 * p;          // int4 index 0..511 (flat coalesced)
        const int n0 = e4 >> 3;
        const int c0 = (e4 & 7) * 4;
        const int4 v = src[e4];
        idx_s[n0][c0 + 0] = v.x; idx_s[n0][c0 + 1] = v.y;
        idx_s[n0][c0 + 2] = v.z; idx_s[n0][c0 + 3] = v.w;
        const float4 f = srcw[e4];
        w_s[n0][c0 + 0] = f.x; w_s[n0][c0 + 1] = f.y;
        w_s[n0][c0 + 2] = f.z; w_s[n0][c0 + 3] = f.w;
    }
    __syncthreads();

    const int np    = t & 63;                // lane -> n row: banks (np+2d2)%32, free
    const int dbase = t >> 6;
#pragma unroll
    for (int k = 0; k < 4; ++k) {
        const int d2 = dbase * 4 + k;        // 0..15
        const unsigned j0 = (unsigned)idx_s[np][2 * d2];
        const unsigned j1 = (unsigned)idx_s[np][2 * d2 + 1];
        const hp2 wp = __builtin_amdgcn_cvt_pkrtz(w_s[np][2 * d2], w_s[np][2 * d2 + 1]);
        uint2 o;
        o.x = j0 | (j1 << 16);
        o.y = __builtin_bit_cast(unsigned, wp);
        pw[(size_t)d2 * NB + nb + np] = o;   // consecutive lanes -> contiguous
    }
}

__global__ __launch_bounds__(512) void fused_gather_kernel(
    const float* __restrict__ x, const uint2* __restrict__ pw,
    float* __restrict__ out) {
    __shared__ unsigned xh[NB];              // 64 KiB: xh[j] = h2(x[b0][j], x[b1][j])
    const int t    = threadIdx.x;
    const int bg   = (int)blockIdx.x >> 1;   // 0..127: batch row pair
    const int half = (int)blockIdx.x & 1;    // n-split (pair shares x rows in L2)
    const int b0   = bg * 2;
    const float* xr0 = x + (size_t)b0 * NB;
    const float* xr1 = xr0 + NB;

    // Stage both rows into LDS as packed fp16 pairs (coalesced float4 reads,
    // stride-16B ds_write_b128 -> throughput-floor, no conflicts).
#pragma unroll
    for (int p = 0; p < 8; ++p) {
        const int j = 4 * (t + 512 * p);
        const float4 a0 = *(const float4*)&xr0[j];
        const float4 a1 = *(const float4*)&xr1[j];
        uint4 o;
        o.x = __builtin_bit_cast(unsigned, (hp2)__builtin_amdgcn_cvt_pkrtz(a0.x, a1.x));
        o.y = __builtin_bit_cast(unsigned, (hp2)__builtin_amdgcn_cvt_pkrtz(a0.y, a1.y));
        o.z = __builtin_bit_cast(unsigned, (hp2)__builtin_amdgcn_cvt_pkrtz(a0.z, a1.z));
        o.w = __builtin_bit_cast(unsigned, (hp2)__builtin_amdgcn_cvt_pkrtz(a0.w, a1.w));
        *(uint4*)&xh[j] = o;
    }
    __syncthreads();

    const int nbase = half * 8192;
#pragma unroll 2
    for (int i = 0; i < 16; ++i) {
        const int n = nbase + t + 512 * i;   // consecutive lanes -> consecutive n
        uint2 q[16];
#pragma unroll
        for (int d2 = 0; d2 < 16; ++d2)      // 16 coalesced dwordx2 (512 B/wave)
            q[d2] = pw[(size_t)d2 * NB + n];

        float acc0 = 0.f, acc1 = 0.f;
#pragma unroll
        for (int d2 = 0; d2 < 16; ++d2) {
            const unsigned jp = q[d2].x;
            const unsigned r0 = xh[jp & 0xffffu];   // ds_read_b32, bank = j%32
            const unsigned r1 = xh[jp >> 16];
            const hp2 w2 = __builtin_bit_cast(hp2, q[d2].y);
            const hp2 p0 = __builtin_bit_cast(hp2, r0);
            const hp2 p1 = __builtin_bit_cast(hp2, r1);
            acc0 = fmaf((float)w2.x, (float)p0.x, acc0);
            acc1 = fmaf((float)w2.x, (float)p0.y, acc1);
            acc0 = fmaf((float)w2.y, (float)p1.x, acc0);
            acc1 = fmaf((float)w2.y, (float)p1.y, acc1);
        }
        out[(size_t)b0 * NB + n]       = fmaxf(acc0, 0.f);
        out[(size_t)(b0 + 1) * NB + n] = fmaxf(acc1, 0.f);
    }
}

extern "C" void kernel_launch(void* const* d_in, const int* in_sizes, int n_in,
                              void* d_out, int out_size, void* d_ws, size_t ws_size,
                              hipStream_t stream) {
    const float* x   = (const float*)d_in[0];    // (B, N)
    const float* w   = (const float*)d_in[1];    // (N, DEG)
    const int*   idx = (const int*)d_in[2];      // (N, DEG)
    float* out = (float*)d_out;                  // (B, N)
    uint2* pw  = (uint2*)d_ws;                   // [16][N] {jpair, wpair} = 2 MiB

    prep_pw_kernel<<<NB / 64, 256, 0, stream>>>(idx, w, pw);

    fused_gather_kernel<<<256, 512, 0, stream>>>(x, pw, out);
}

// Round 8
// 90.610 us; speedup vs baseline: 1.0669x; 1.0669x over previous
//
#include <hip/hip_runtime.h>

// out[b,n] = relu( sum_d x[b, idx[n,d]] * w[n,d] )
//   x: (B=256, N=16384) f32, w: (N,32) f32, idx: (N,32) i32, out: (B,N) f32
//
// R8: LDS gather, but 4 batches per ds_read_b64 (2048 DS instr/CU vs R7's
// 4096 b32), 16 waves/CU (1024-thr blocks), and v_pk_fma_f16 math.
//   K0 (fused): pack pw[d2][n] = {j0|j1<<16, h2(w0,w1)}  (2 MiB)
//               pack xq[quad][j] = {h2(b0,b1), h2(b2,b3)} (8 MiB), quad = b/4
//   K1: block = quad x n-split(4096). Stage quad image (128 KiB) -> LDS,
//       gather via ds_read_b64, pk_fma accumulate, f32 relu stores.

#define NB   16384
#define DEG  32

typedef __fp16 hp2 __attribute__((ext_vector_type(2)));  // cvt_pkrtz result type

__device__ __forceinline__ unsigned pk16(float a, float b) {
    return __builtin_bit_cast(unsigned, (hp2)__builtin_amdgcn_cvt_pkrtz(a, b));
}

// blocks [0, 4096): pack xq. blocks [4096, 4352): pack pw.
__global__ __launch_bounds__(256) void prep_kernel(
    const int* __restrict__ idx, const float* __restrict__ w,
    const float* __restrict__ x, uint2* __restrict__ pw,
    uint2* __restrict__ xq) {
    __shared__ int   idx_s[64][33];
    __shared__ float w_s[64][33];
    const int t = threadIdx.x;

    if (blockIdx.x < 4096) {
        const int jt = (int)blockIdx.x & 63;     // j-tile of 256
        const int q  = (int)blockIdx.x >> 6;     // quad 0..63
        const int j  = jt * 256 + t;
        const float* xr = x + (size_t)(4 * q) * NB + j;
        const float a0 = xr[0];
        const float a1 = xr[NB];
        const float a2 = xr[2 * NB];
        const float a3 = xr[3 * NB];
        uint2 o;
        o.x = pk16(a0, a1);
        o.y = pk16(a2, a3);
        xq[((size_t)q << 14) + j] = o;
        return;
    }

    const int nb = ((int)blockIdx.x - 4096) * 64;
    const int4*   src  = (const int4*)(idx + (size_t)nb * DEG);
    const float4* srcw = (const float4*)(w   + (size_t)nb * DEG);
#pragma unroll
    for (int p = 0; p < 2; ++p) {
        const int e4 = t + 256 * p;              // int4 index 0..511, coalesced
        const int n0 = e4 >> 3;
        const int c0 = (e4 & 7) * 4;
        const int4 v = src[e4];
        idx_s[n0][c0 + 0] = v.x; idx_s[n0][c0 + 1] = v.y;
        idx_s[n0][c0 + 2] = v.z; idx_s[n0][c0 + 3] = v.w;
        const float4 f = srcw[e4];
        w_s[n0][c0 + 0] = f.x; w_s[n0][c0 + 1] = f.y;
        w_s[n0][c0 + 2] = f.z; w_s[n0][c0 + 3] = f.w;
    }
    __syncthreads();

    const int np    = t & 63;
    const int dbase = t >> 6;
#pragma unroll
    for (int k = 0; k < 4; ++k) {
        const int d2 = dbase * 4 + k;            // 0..15
        uint2 o;
        o.x = (unsigned)idx_s[np][2 * d2] | ((unsigned)idx_s[np][2 * d2 + 1] << 16);
        o.y = pk16(w_s[np][2 * d2], w_s[np][2 * d2 + 1]);
        pw[(size_t)d2 * NB + nb + np] = o;
    }
}

__global__ __launch_bounds__(1024) void gather4_kernel(
    const uint2* __restrict__ xq, const uint2* __restrict__ pw,
    float* __restrict__ out) {
    extern __shared__ uint2 lds[];               // 16384 uint2 = 128 KiB
    const int t  = threadIdx.x;
    const int q  = (int)blockIdx.x >> 2;         // quad 0..63 -> b = 4q..4q+3
    const int n0 = ((int)blockIdx.x & 3) * 4096;

    // Stage the quad's full j-image: coalesced uint4 global reads,
    // consecutive-lane ds_write_b128 (canonical conflict-free pattern).
    {
        const uint4* src = (const uint4*)(xq + ((size_t)q << 14));
        uint4* dst = (uint4*)lds;
#pragma unroll
        for (int i = 0; i < 8; ++i) dst[t + 1024 * i] = src[t + 1024 * i];
    }
    __syncthreads();

    const int b0 = 4 * q;
    for (int i = 0; i < 4; ++i) {
        const int n = n0 + t + 1024 * i;         // consecutive lanes -> consec n
        uint2 qd[16];
#pragma unroll
        for (int d2 = 0; d2 < 16; ++d2)          // 16 coalesced dwordx2 streams
            qd[d2] = pw[(size_t)d2 * NB + n];

        hp2 a01 = {0, 0}, a23 = {0, 0}, c01 = {0, 0}, c23 = {0, 0};
#pragma unroll
        for (int d2 = 0; d2 < 8; ++d2) {
            const unsigned jp = qd[d2].x;
            const uint2 g0 = lds[jp & 0xffffu];  // ds_read_b64: 4 batches/read
            const uint2 g1 = lds[jp >> 16];
            const hp2 w2 = __builtin_bit_cast(hp2, qd[d2].y);
            const hp2 wlo = {w2.x, w2.x};
            const hp2 whi = {w2.y, w2.y};
            a01 += wlo * __builtin_bit_cast(hp2, g0.x);   // v_pk_fma_f16
            a23 += wlo * __builtin_bit_cast(hp2, g0.y);
            a01 += whi * __builtin_bit_cast(hp2, g1.x);
            a23 += whi * __builtin_bit_cast(hp2, g1.y);
        }
#pragma unroll
        for (int d2 = 8; d2 < 16; ++d2) {
            const unsigned jp = qd[d2].x;
            const uint2 g0 = lds[jp & 0xffffu];
            const uint2 g1 = lds[jp >> 16];
            const hp2 w2 = __builtin_bit_cast(hp2, qd[d2].y);
            const hp2 wlo = {w2.x, w2.x};
            const hp2 whi = {w2.y, w2.y};
            c01 += wlo * __builtin_bit_cast(hp2, g0.x);
            c23 += wlo * __builtin_bit_cast(hp2, g0.y);
            c01 += whi * __builtin_bit_cast(hp2, g1.x);
            c23 += whi * __builtin_bit_cast(hp2, g1.y);
        }
        const hp2 s01 = a01 + c01;
        const hp2 s23 = a23 + c23;
        out[(size_t)(b0 + 0) * NB + n] = fmaxf((float)s01.x, 0.f);
        out[(size_t)(b0 + 1) * NB + n] = fmaxf((float)s01.y, 0.f);
        out[(size_t)(b0 + 2) * NB + n] = fmaxf((float)s23.x, 0.f);
        out[(size_t)(b0 + 3) * NB + n] = fmaxf((float)s23.y, 0.f);
    }
}

extern "C" void kernel_launch(void* const* d_in, const int* in_sizes, int n_in,
                              void* d_out, int out_size, void* d_ws, size_t ws_size,
                              hipStream_t stream) {
    const float* x   = (const float*)d_in[0];    // (B, N)
    const float* w   = (const float*)d_in[1];    // (N, DEG)
    const int*   idx = (const int*)d_in[2];      // (N, DEG)
    float* out = (float*)d_out;                  // (B, N)
    uint2* pw  = (uint2*)d_ws;                   // [16][N]    = 2 MiB
    uint2* xq  = (uint2*)((char*)d_ws + (2u << 20));  // [64][N] = 8 MiB

    // allow 128 KiB dynamic LDS (idempotent; host-side, capture-safe)
    (void)hipFuncSetAttribute((const void*)gather4_kernel,
                              hipFuncAttributeMaxDynamicSharedMemorySize, 131072);

    prep_kernel<<<4096 + NB / 64, 256, 0, stream>>>(idx, w, x, pw, xq);

    gather4_kernel<<<256, 1024, 131072, stream>>>(xq, pw, out);
}

// Round 9
// 84.751 us; speedup vs baseline: 1.1406x; 1.0691x over previous
//
#include <hip/hip_runtime.h>

// out[b,n] = relu( sum_d x[b, idx[n,d]] * w[n,d] )
//   x: (B=256, N=16384) f32, w: (N,32) f32, idx: (N,32) i32, out: (B,N) f32
//
// R9: R8 structure (LDS gather, ds_read_b64 quads, pk_fma) minus the xq
// middleman: gather4 stages x -> LDS h2 directly (prep was 4096 blocks just
// to round-trip 40 MB through HBM). prep now packs only pw (256 blocks).
// Grid order split*64+q puts all 4 n-splits of quad q on XCD q%8 (x rows
// fetched once per XCD; pw 2 MiB + 8 quad-images 2 MiB fit the 4 MiB L2).
// __launch_bounds__(1024,4) pins 16 waves/CU for DS latency hiding.

#define NB   16384
#define DEG  32

typedef __fp16 hp2 __attribute__((ext_vector_type(2)));  // cvt_pkrtz result type

__device__ __forceinline__ unsigned pk16(float a, float b) {
    return __builtin_bit_cast(unsigned, (hp2)__builtin_amdgcn_cvt_pkrtz(a, b));
}

__global__ __launch_bounds__(256) void prep_pw_kernel(
    const int* __restrict__ idx, const float* __restrict__ w,
    uint2* __restrict__ pw) {
    __shared__ int   idx_s[64][33];
    __shared__ float w_s[64][33];
    const int t  = threadIdx.x;
    const int nb = (int)blockIdx.x * 64;

    const int4*   src  = (const int4*)(idx + (size_t)nb * DEG);
    const float4* srcw = (const float4*)(w   + (size_t)nb * DEG);
#pragma unroll
    for (int p = 0; p < 2; ++p) {
        const int e4 = t + 256 * p;              // int4 index 0..511, coalesced
        const int n0 = e4 >> 3;
        const int c0 = (e4 & 7) * 4;
        const int4 v = src[e4];
        idx_s[n0][c0 + 0] = v.x; idx_s[n0][c0 + 1] = v.y;
        idx_s[n0][c0 + 2] = v.z; idx_s[n0][c0 + 3] = v.w;
        const float4 f = srcw[e4];
        w_s[n0][c0 + 0] = f.x; w_s[n0][c0 + 1] = f.y;
        w_s[n0][c0 + 2] = f.z; w_s[n0][c0 + 3] = f.w;
    }
    __syncthreads();

    const int np    = t & 63;
    const int dbase = t >> 6;
#pragma unroll
    for (int k = 0; k < 4; ++k) {
        const int d2 = dbase * 4 + k;            // 0..15
        uint2 o;
        o.x = (unsigned)idx_s[np][2 * d2] | ((unsigned)idx_s[np][2 * d2 + 1] << 16);
        o.y = pk16(w_s[np][2 * d2], w_s[np][2 * d2 + 1]);
        pw[(size_t)d2 * NB + nb + np] = o;
    }
}

__global__ __launch_bounds__(1024, 4) void gather4_kernel(
    const float* __restrict__ x, const uint2* __restrict__ pw,
    float* __restrict__ out) {
    extern __shared__ uint2 lds[];               // 16384 uint2 = 128 KiB
    const int t  = threadIdx.x;
    const int q  = (int)blockIdx.x & 63;         // quad 0..63 -> b = 4q..4q+3
    const int n0 = ((int)blockIdx.x >> 6) * 4096;  // split-major: XCD = q%8

    // Stage quad j-image straight from x (coalesced float4 per row; rows are
    // L2-hot for 3 of the 4 split-blocks). ds_write_b128 stride-32B: clean.
    const float* xr0 = x + (size_t)(4 * q) * NB;
    const float* xr1 = xr0 + NB;
    const float* xr2 = xr1 + NB;
    const float* xr3 = xr2 + NB;
#pragma unroll
    for (int p = 0; p < 4; ++p) {
        const int j = 4 * (t + 1024 * p);
        const float4 r0 = *(const float4*)&xr0[j];
        const float4 r1 = *(const float4*)&xr1[j];
        const float4 r2 = *(const float4*)&xr2[j];
        const float4 r3 = *(const float4*)&xr3[j];
        uint4 w0, w1;
        w0.x = pk16(r0.x, r1.x); w0.y = pk16(r2.x, r3.x);
        w0.z = pk16(r0.y, r1.y); w0.w = pk16(r2.y, r3.y);
        w1.x = pk16(r0.z, r1.z); w1.y = pk16(r2.z, r3.z);
        w1.z = pk16(r0.w, r1.w); w1.w = pk16(r2.w, r3.w);
        *(uint4*)&lds[j]     = w0;
        *(uint4*)&lds[j + 2] = w1;
    }
    __syncthreads();

    const int b0 = 4 * q;
    for (int i = 0; i < 4; ++i) {
        const int n = n0 + t + 1024 * i;         // consecutive lanes -> consec n
        uint2 qd[16];
#pragma unroll
        for (int d2 = 0; d2 < 16; ++d2)          // 16 coalesced dwordx2 streams
            qd[d2] = pw[(size_t)d2 * NB + n];

        hp2 a01 = {0, 0}, a23 = {0, 0}, c01 = {0, 0}, c23 = {0, 0};
#pragma unroll
        for (int d2 = 0; d2 < 8; ++d2) {
            const unsigned jp = qd[d2].x;
            const uint2 g0 = lds[jp & 0xffffu];  // ds_read_b64: 4 batches/read
            const uint2 g1 = lds[jp >> 16];
            const hp2 w2 = __builtin_bit_cast(hp2, qd[d2].y);
            const hp2 wlo = {w2.x, w2.x};
            const hp2 whi = {w2.y, w2.y};
            a01 += wlo * __builtin_bit_cast(hp2, g0.x);   // v_pk_fma_f16
            a23 += wlo * __builtin_bit_cast(hp2, g0.y);
            a01 += whi * __builtin_bit_cast(hp2, g1.x);
            a23 += whi * __builtin_bit_cast(hp2, g1.y);
        }
#pragma unroll
        for (int d2 = 8; d2 < 16; ++d2) {
            const unsigned jp = qd[d2].x;
            const uint2 g0 = lds[jp & 0xffffu];
            const uint2 g1 = lds[jp >> 16];
            const hp2 w2 = __builtin_bit_cast(hp2, qd[d2].y);
            const hp2 wlo = {w2.x, w2.x};
            const hp2 whi = {w2.y, w2.y};
            c01 += wlo * __builtin_bit_cast(hp2, g0.x);
            c23 += wlo * __builtin_bit_cast(hp2, g0.y);
            c01 += whi * __builtin_bit_cast(hp2, g1.x);
            c23 += whi * __builtin_bit_cast(hp2, g1.y);
        }
        const hp2 s01 = a01 + c01;
        const hp2 s23 = a23 + c23;
        out[(size_t)(b0 + 0) * NB + n] = fmaxf((float)s01.x, 0.f);
        out[(size_t)(b0 + 1) * NB + n] = fmaxf((float)s01.y, 0.f);
        out[(size_t)(b0 + 2) * NB + n] = fmaxf((float)s23.x, 0.f);
        out[(size_t)(b0 + 3) * NB + n] = fmaxf((float)s23.y, 0.f);
    }
}

extern "C" void kernel_launch(void* const* d_in, const int* in_sizes, int n_in,
                              void* d_out, int out_size, void* d_ws, size_t ws_size,
                              hipStream_t stream) {
    const float* x   = (const float*)d_in[0];    // (B, N)
    const float* w   = (const float*)d_in[1];    // (N, DEG)
    const int*   idx = (const int*)d_in[2];      // (N, DEG)
    float* out = (float*)d_out;                  // (B, N)
    uint2* pw  = (uint2*)d_ws;                   // [16][N] = 2 MiB

    // allow 128 KiB dynamic LDS (idempotent; host-side, capture-safe)
    (void)hipFuncSetAttribute((const void*)gather4_kernel,
                              hipFuncAttributeMaxDynamicSharedMemorySize, 131072);

    prep_pw_kernel<<<NB / 64, 256, 0, stream>>>(idx, w, pw);

    gather4_kernel<<<256, 1024, 131072, stream>>>(x, pw, out);
}